// Round 13
// baseline (223.410 us; speedup 1.0000x reference)
//
#include <hip/hip_runtime.h>
#include <hip/hip_bf16.h>
#include <cstddef>

#define NN 50000
#define NR 8
#define NE 800000
#define DD 128
#define KTOT 1024                    // NR * DD
#define NB (NN * NR)                 // sort bins: key = dst*8 + rel
#define NSCAN ((NB + 1023) / 1024)   // 391
#define XPAD 136

#define HIST_BLOCKS ((NE + 255) / 256)       // 3125
#define NXCVT (NN * DD / 8)                  // 800000
#define NWCVT (9 * DD * DD)                  // 147456
#define CVT_BLOCKS ((NXCVT + NWCVT + 255) / 256)

typedef __bf16 bf16x8 __attribute__((ext_vector_type(8)));
typedef float  f32x4  __attribute__((ext_vector_type(4)));

// ---------------------------------------------------------------------------
// hist (counting sort pass 1) fused with X/W -> bf16 conversion  [proven r7-r12]
// ---------------------------------------------------------------------------
__global__ __launch_bounds__(256) void histcvt_kernel(
    const int* __restrict__ dst, const int* __restrict__ rel, int* __restrict__ cnt,
    const float* __restrict__ X, __hip_bfloat16* __restrict__ Xb,
    const float* __restrict__ W, const float* __restrict__ W0,
    __hip_bfloat16* __restrict__ Wt)
{
    const int bid = blockIdx.x;
    if (bid < HIST_BLOCKS) {
        const int e = bid * 256 + threadIdx.x;
        if (e < NE) atomicAdd(&cnt[dst[e] * NR + rel[e]], 1);
    } else {
        const int i = (bid - HIST_BLOCKS) * 256 + threadIdx.x;
        if (i < NXCVT) {
            const float4* xp = (const float4*)(X + (size_t)i * 8);
            const float4 a = xp[0], b = xp[1];
            __bf16 h[8] = {(__bf16)a.x, (__bf16)a.y, (__bf16)a.z, (__bf16)a.w,
                           (__bf16)b.x, (__bf16)b.y, (__bf16)b.z, (__bf16)b.w};
            *(uint4*)(Xb + (size_t)i * 8) = *(uint4*)h;
        } else {
            const int idx = i - NXCVT;
            if (idx < NWCVT) {
                const int c = idx >> 14;
                const int r = idx & 16383;
                const int n = r >> 7, k = r & 127;
                const float v = (c < NR) ? W[(size_t)c * DD * DD + k * DD + n]
                                         : W0[k * DD + n];
                Wt[idx] = __float2bfloat16(v);
            }
        }
    }
}

// 3-pass parallel exclusive scan over NB bins  [proven r4-r12]
__global__ __launch_bounds__(1024) void scan1_kernel(
    const int* __restrict__ cnt, int* __restrict__ offsets, int* __restrict__ blockSums)
{
    __shared__ int sm[1024];
    const int t = threadIdx.x;
    const int i = blockIdx.x * 1024 + t;
    const int v = (i < NB) ? cnt[i] : 0;
    sm[t] = v;
    __syncthreads();
    #pragma unroll
    for (int off = 1; off < 1024; off <<= 1) {
        int u = (t >= off) ? sm[t - off] : 0;
        __syncthreads();
        sm[t] += u;
        __syncthreads();
    }
    if (i < NB) offsets[i] = sm[t] - v;
    if (t == 1023) blockSums[blockIdx.x] = sm[1023];
}

__global__ __launch_bounds__(512) void scan2_kernel(int* __restrict__ blockSums)
{
    __shared__ int sm[512];
    const int t = threadIdx.x;
    const int v = (t < NSCAN) ? blockSums[t] : 0;
    sm[t] = v;
    __syncthreads();
    #pragma unroll
    for (int off = 1; off < 512; off <<= 1) {
        int u = (t >= off) ? sm[t - off] : 0;
        __syncthreads();
        sm[t] += u;
        __syncthreads();
    }
    if (t < NSCAN) blockSums[t] = sm[t] - v;
}

__global__ __launch_bounds__(1024) void scan3_kernel(
    int* __restrict__ offsets, int* __restrict__ cursor, const int* __restrict__ blockSums)
{
    const int i = blockIdx.x * 1024 + threadIdx.x;
    if (i < NB) {
        const int o = offsets[i] + blockSums[blockIdx.x];
        offsets[i] = o;
        cursor[i]  = o;
    }
    if (blockIdx.x == 0 && threadIdx.x == 0) offsets[NB] = NE;
}

__global__ __launch_bounds__(256) void scatter_kernel(
    const int* __restrict__ src, const int* __restrict__ dst,
    const int* __restrict__ rel, int* __restrict__ cursor,
    unsigned* __restrict__ packed)
{
    int e = blockIdx.x * 256 + threadIdx.x;
    if (e < NE) {
        const int key = dst[e] * NR + rel[e];
        const int pos = atomicAdd(&cursor[key], 1);
        packed[pos] = (unsigned)src[e];
    }
}

// ---------------------------------------------------------------------------
// Phase B v3 [proven r10]: one wave per NODE (8 segments). Quarter q owns
// relations q and q+4: 2 chains x unroll-2 = 16 loads in flight per wave.
// ---------------------------------------------------------------------------
__device__ __forceinline__ void accum8(float* acc, const uint4 u)
{
    const unsigned w[4] = {u.x, u.y, u.z, u.w};
    #pragma unroll
    for (int j = 0; j < 4; ++j) {
        acc[2 * j]     += __uint_as_float(w[j] << 16);
        acc[2 * j + 1] += __uint_as_float(w[j] & 0xFFFF0000u);
    }
}

__global__ __launch_bounds__(256) void agg_bf16_kernel(
    const __hip_bfloat16* __restrict__ Xb, const float* __restrict__ inv_norm,
    const int* __restrict__ offsets, const unsigned* __restrict__ packed,
    __hip_bfloat16* __restrict__ A)
{
    const int tid  = threadIdx.x;
    const int q    = (tid >> 4) & 3;                 // quarter 0..3
    const int l    = tid & 15;                       // lane in quarter
    const int node = blockIdx.x * 4 + (tid >> 6);    // wave -> node
    if (node >= NN) return;

    const int sA = node * NR + q;                    // relation q
    const int sB = sA + 4;                           // relation q+4

    int eA = offsets[sA];
    const int endA = offsets[sA + 1];
    int eB = offsets[sB];
    const int endB = offsets[sB + 1];

    float aA[8] = {0.f,0.f,0.f,0.f,0.f,0.f,0.f,0.f};
    float aB[8] = {0.f,0.f,0.f,0.f,0.f,0.f,0.f,0.f};

    while (__any((eA + 2 <= endA) || (eB + 2 <= endB))) {
        const bool dA = (eA + 2 <= endA);
        const bool dB = (eB + 2 <= endB);
        uint4 u0, u1, v0, v1;
        if (dA) {
            u0 = *(const uint4*)(Xb + (size_t)packed[eA] * DD + l * 8);
            u1 = *(const uint4*)(Xb + (size_t)packed[eA + 1] * DD + l * 8);
        }
        if (dB) {
            v0 = *(const uint4*)(Xb + (size_t)packed[eB] * DD + l * 8);
            v1 = *(const uint4*)(Xb + (size_t)packed[eB + 1] * DD + l * 8);
        }
        if (dA) { accum8(aA, u0); accum8(aA, u1); eA += 2; }
        if (dB) { accum8(aB, v0); accum8(aB, v1); eB += 2; }
    }
    if (eA < endA) {
        const uint4 u0 = *(const uint4*)(Xb + (size_t)packed[eA] * DD + l * 8);
        accum8(aA, u0);
    }
    if (eB < endB) {
        const uint4 v0 = *(const uint4*)(Xb + (size_t)packed[eB] * DD + l * 8);
        accum8(aB, v0);
    }

    const float invA = inv_norm[sA];
    const float invB = inv_norm[sB];
    __bf16 hA[8], hB[8];
    #pragma unroll
    for (int j = 0; j < 8; ++j) {
        hA[j] = (__bf16)(aA[j] * invA);
        hB[j] = (__bf16)(aB[j] * invB);
    }
    *(uint4*)(A + (size_t)node * KTOT + q * DD + l * 8)       = *(uint4*)hA;
    *(uint4*)(A + (size_t)node * KTOT + (q + 4) * DD + l * 8) = *(uint4*)hB;
}

// ---------------------------------------------------------------------------
// Phase C v3: HYBRID GEMM.  out = [A | Xb] @ [Wt stack]  (K = 1152, 9 chunks)
// B staged in LDS (4-wave reuse, swizzled — identical to r10's proven path);
// A loaded DIRECT from global per fragment (zero reuse — r12's proven
// addressing, bit-identical math). 64-row tiles -> 782 blocks, 32 KB LDS ->
// ~3 blocks/CU resident so A-load latency hides behind other waves' MFMAs.
// Waves: wr = rows wr*32..+31 (mf 0..1), wc = cols wc*64..+63 (nf 0..3).
// ---------------------------------------------------------------------------
__global__ __launch_bounds__(256) void mfma_gemm_kernel(
    const __hip_bfloat16* __restrict__ A, const __hip_bfloat16* __restrict__ Xb,
    const __hip_bfloat16* __restrict__ Wt, float* __restrict__ out)
{
    __shared__ __align__(16) char Bs[128 * 256];   // 32 KB

    const int tid  = threadIdx.x;
    const int n0   = blockIdx.x * 64;
    const int lane = tid & 63;
    const int wid  = tid >> 6;
    const int wr   = wid >> 1, wc = wid & 1;
    const int l15  = lane & 15, kg = lane >> 4;

    bf16x8 zero8;
    #pragma unroll
    for (int j = 0; j < 8; ++j) zero8[j] = (__bf16)0.f;

    f32x4 acc[2][4];
    #pragma unroll
    for (int mf = 0; mf < 2; ++mf)
        #pragma unroll
        for (int nf = 0; nf < 4; ++nf)
            acc[mf][nf] = (f32x4){0.f, 0.f, 0.f, 0.f};

    for (int c = 0; c < NR + 1; ++c) {
        // ---- stage Bs = Wt[c] (128 cols x 128 k, bf16, swizzled) [r10 path]
        {
            const __hip_bfloat16* Wc = Wt + (size_t)c * DD * DD;
            #pragma unroll
            for (int it = 0; it < 8; ++it) {
                const int idx = tid + it * 256;
                const int row = idx >> 4, b = idx & 15;
                const uint4 v = *(const uint4*)(Wc + (size_t)row * DD + b * 8);
                *(uint4*)(Bs + row * 256 + ((b ^ (row & 7)) << 4)) = v;
            }
        }
        __syncthreads();

        const __hip_bfloat16* __restrict__ Ab =
            (c < NR) ? (A + (size_t)c * DD) : Xb;
        const size_t astr = (c < NR) ? (size_t)KTOT : (size_t)DD;

        #pragma unroll
        for (int ks = 0; ks < 4; ++ks) {
            const int b    = ks * 4 + kg;
            const int koff = b * 8;
            bf16x8 af[2], bfr[4];
            #pragma unroll
            for (int mf = 0; mf < 2; ++mf) {
                const int row = n0 + wr * 32 + mf * 16 + l15;
                af[mf] = (row < NN)
                    ? *(const bf16x8*)(Ab + (size_t)row * astr + koff)
                    : zero8;
            }
            #pragma unroll
            for (int nf = 0; nf < 4; ++nf) {
                const int brow = wc * 64 + nf * 16 + l15;
                bfr[nf] = *(const bf16x8*)(Bs + brow * 256 + ((b ^ (brow & 7)) << 4));
            }
            #pragma unroll
            for (int mf = 0; mf < 2; ++mf)
                #pragma unroll
                for (int nf = 0; nf < 4; ++nf)
                    acc[mf][nf] = __builtin_amdgcn_mfma_f32_16x16x32_bf16(
                        af[mf], bfr[nf], acc[mf][nf], 0, 0, 0);
        }
        __syncthreads();
    }

    // epilogue: C/D layout col=lane&15, row=(lane>>4)*4+reg  [m89/m91]
    #pragma unroll
    for (int mf = 0; mf < 2; ++mf) {
        #pragma unroll
        for (int reg = 0; reg < 4; ++reg) {
            const int n = n0 + wr * 32 + mf * 16 + kg * 4 + reg;
            if (n < NN) {
                #pragma unroll
                for (int nf = 0; nf < 4; ++nf)
                    out[(size_t)n * DD + wc * 64 + nf * 16 + l15] = acc[mf][nf][reg];
            }
        }
    }
}

// ---------------------------------------------------------------------------
// Fallback (ws too small)
// ---------------------------------------------------------------------------
__global__ __launch_bounds__(256) void xform0_kernel(
    const float* __restrict__ X, const float* __restrict__ W0, float* __restrict__ out)
{
    __shared__ __align__(16) float Xs[64][XPAD];
    const int n0 = blockIdx.x * 64;
    const int tid = threadIdx.x;
    for (int t = tid; t < 64 * 32; t += 256) {
        const int row = t >> 5, g = t & 31;
        const int n = n0 + row;
        float4 v = make_float4(0.f, 0.f, 0.f, 0.f);
        if (n < NN) v = ((const float4*)(X + (size_t)n * DD))[g];
        *(float4*)&Xs[row][g * 4] = v;
    }
    __syncthreads();
    const int to = tid & 31, tn = tid >> 5;
    float acc[8][4];
    #pragma unroll
    for (int k = 0; k < 8; ++k)
        #pragma unroll
        for (int j = 0; j < 4; ++j) acc[k][j] = 0.f;
    for (int i = 0; i < DD; ++i) {
        const float4 w = ((const float4*)(W0 + (size_t)i * DD))[to];
        #pragma unroll
        for (int k = 0; k < 8; ++k) {
            const float xs = Xs[tn * 8 + k][i];
            acc[k][0] += xs * w.x; acc[k][1] += xs * w.y;
            acc[k][2] += xs * w.z; acc[k][3] += xs * w.w;
        }
    }
    #pragma unroll
    for (int k = 0; k < 8; ++k) {
        const int n = n0 + tn * 8 + k;
        if (n < NN)
            ((float4*)(out + (size_t)n * DD))[to] =
                make_float4(acc[k][0], acc[k][1], acc[k][2], acc[k][3]);
    }
}

__global__ __launch_bounds__(128) void edge_fallback_kernel(
    const float* __restrict__ X, const float* __restrict__ W,
    const float* __restrict__ inv_norm,
    const int* __restrict__ src, const int* __restrict__ dst,
    const int* __restrict__ rel, float* __restrict__ out)
{
    const int o = threadIdx.x;
    for (int e = blockIdx.x; e < NE; e += gridDim.x) {
        const int s = src[e], d = dst[e], r = rel[e];
        const float inv = inv_norm[(size_t)d * NR + r];
        const float* Xr = X + (size_t)s * DD;
        const float* Wr = W + (size_t)r * DD * DD;
        float a = 0.f;
        for (int i = 0; i < DD; ++i) a += Xr[i] * Wr[i * DD + o];
        unsafeAtomicAdd(out + (size_t)d * DD + o, a * inv);
    }
}

// ---------------------------------------------------------------------------
extern "C" void kernel_launch(void* const* d_in, const int* in_sizes, int n_in,
                              void* d_out, int out_size, void* d_ws, size_t ws_size,
                              hipStream_t stream)
{
    const float* X        = (const float*)d_in[0];
    const float* W        = (const float*)d_in[1];
    const float* W0       = (const float*)d_in[2];
    const float* inv_norm = (const float*)d_in[3];
    const int*   src      = (const int*)d_in[4];
    const int*   dst      = (const int*)d_in[5];
    const int*   rel      = (const int*)d_in[6];
    float* out = (float*)d_out;

    char* ws = (char*)d_ws;
    size_t off = 0;
    auto alloc = [&](size_t bytes) {
        void* p = ws + off;
        off += (bytes + 255) & ~(size_t)255;
        return p;
    };
    __hip_bfloat16* A  = (__hip_bfloat16*)alloc((size_t)NN * KTOT * sizeof(__hip_bfloat16));
    int*      offsets  = (int*)alloc((size_t)(NB + 1) * sizeof(int));
    int*      cursor   = (int*)alloc((size_t)NB * sizeof(int));
    int*      cnt      = (int*)alloc((size_t)NB * sizeof(int));
    unsigned* packed   = (unsigned*)alloc((size_t)NE * sizeof(unsigned));
    __hip_bfloat16* Wt = (__hip_bfloat16*)alloc((size_t)9 * DD * DD * sizeof(__hip_bfloat16));
    int*    blockSums  = (int*)alloc((size_t)NSCAN * sizeof(int));
    __hip_bfloat16* Xb = (__hip_bfloat16*)alloc((size_t)NN * DD * sizeof(__hip_bfloat16));

    if (ws_size >= off) {
        hipMemsetAsync(cnt, 0, (size_t)NB * sizeof(int), stream);
        histcvt_kernel<<<HIST_BLOCKS + CVT_BLOCKS, 256, 0, stream>>>(
            dst, rel, cnt, X, Xb, W, W0, Wt);
        scan1_kernel<<<NSCAN, 1024, 0, stream>>>(cnt, offsets, blockSums);
        scan2_kernel<<<1, 512, 0, stream>>>(blockSums);
        scan3_kernel<<<NSCAN, 1024, 0, stream>>>(offsets, cursor, blockSums);
        scatter_kernel<<<(NE + 255) / 256, 256, 0, stream>>>(src, dst, rel, cursor, packed);
        agg_bf16_kernel<<<(NN + 3) / 4, 256, 0, stream>>>(
            Xb, inv_norm, offsets, packed, A);
        mfma_gemm_kernel<<<(NN + 63) / 64, 256, 0, stream>>>(A, Xb, Wt, out);
    } else {
        xform0_kernel<<<(NN + 63) / 64, 256, 0, stream>>>(X, W0, out);
        edge_fallback_kernel<<<8192, 128, 0, stream>>>(X, W, inv_norm, src, dst, rel, out);
    }
}

// Round 14
// 188.754 us; speedup vs baseline: 1.1836x; 1.1836x over previous
//
#include <hip/hip_runtime.h>
#include <hip/hip_bf16.h>
#include <cstddef>

#define NN 50000
#define NR 8
#define NE 800000
#define DD 128
#define KTOT 1024                    // NR * DD
#define NB (NN * NR)                 // sort bins: key = dst*8 + rel
#define NSCAN ((NB + 1023) / 1024)   // 391
#define XPAD 136

#define HIST_BLOCKS ((NE + 255) / 256)       // 3125
#define NXCVT (NN * DD / 8)                  // 800000
#define NWCVT (9 * DD * DD)                  // 147456
#define CVT_BLOCKS ((NXCVT + NWCVT + 255) / 256)

typedef __bf16 bf16x8 __attribute__((ext_vector_type(8)));
typedef float  f32x4  __attribute__((ext_vector_type(4)));

// direct global->LDS DMA, 16 B per lane; LDS dest = wave-uniform base + lane*16
__device__ __forceinline__ void gload_lds16(const void* g, void* lds)
{
    __builtin_amdgcn_global_load_lds(
        (const __attribute__((address_space(1))) unsigned*)g,
        (__attribute__((address_space(3))) unsigned*)lds, 16, 0, 0);
}

// ---------------------------------------------------------------------------
// hist (counting sort pass 1) fused with X/W -> bf16 conversion  [proven r7-r13]
// ---------------------------------------------------------------------------
__global__ __launch_bounds__(256) void histcvt_kernel(
    const int* __restrict__ dst, const int* __restrict__ rel, int* __restrict__ cnt,
    const float* __restrict__ X, __hip_bfloat16* __restrict__ Xb,
    const float* __restrict__ W, const float* __restrict__ W0,
    __hip_bfloat16* __restrict__ Wt)
{
    const int bid = blockIdx.x;
    if (bid < HIST_BLOCKS) {
        const int e = bid * 256 + threadIdx.x;
        if (e < NE) atomicAdd(&cnt[dst[e] * NR + rel[e]], 1);
    } else {
        const int i = (bid - HIST_BLOCKS) * 256 + threadIdx.x;
        if (i < NXCVT) {
            const float4* xp = (const float4*)(X + (size_t)i * 8);
            const float4 a = xp[0], b = xp[1];
            __bf16 h[8] = {(__bf16)a.x, (__bf16)a.y, (__bf16)a.z, (__bf16)a.w,
                           (__bf16)b.x, (__bf16)b.y, (__bf16)b.z, (__bf16)b.w};
            *(uint4*)(Xb + (size_t)i * 8) = *(uint4*)h;
        } else {
            const int idx = i - NXCVT;
            if (idx < NWCVT) {
                const int c = idx >> 14;
                const int r = idx & 16383;
                const int n = r >> 7, k = r & 127;
                const float v = (c < NR) ? W[(size_t)c * DD * DD + k * DD + n]
                                         : W0[k * DD + n];
                Wt[idx] = __float2bfloat16(v);
            }
        }
    }
}

// 3-pass parallel exclusive scan over NB bins  [proven r4-r13]
__global__ __launch_bounds__(1024) void scan1_kernel(
    const int* __restrict__ cnt, int* __restrict__ offsets, int* __restrict__ blockSums)
{
    __shared__ int sm[1024];
    const int t = threadIdx.x;
    const int i = blockIdx.x * 1024 + t;
    const int v = (i < NB) ? cnt[i] : 0;
    sm[t] = v;
    __syncthreads();
    #pragma unroll
    for (int off = 1; off < 1024; off <<= 1) {
        int u = (t >= off) ? sm[t - off] : 0;
        __syncthreads();
        sm[t] += u;
        __syncthreads();
    }
    if (i < NB) offsets[i] = sm[t] - v;
    if (t == 1023) blockSums[blockIdx.x] = sm[1023];
}

__global__ __launch_bounds__(512) void scan2_kernel(int* __restrict__ blockSums)
{
    __shared__ int sm[512];
    const int t = threadIdx.x;
    const int v = (t < NSCAN) ? blockSums[t] : 0;
    sm[t] = v;
    __syncthreads();
    #pragma unroll
    for (int off = 1; off < 512; off <<= 1) {
        int u = (t >= off) ? sm[t - off] : 0;
        __syncthreads();
        sm[t] += u;
        __syncthreads();
    }
    if (t < NSCAN) blockSums[t] = sm[t] - v;
}

__global__ __launch_bounds__(1024) void scan3_kernel(
    int* __restrict__ offsets, int* __restrict__ cursor, const int* __restrict__ blockSums)
{
    const int i = blockIdx.x * 1024 + threadIdx.x;
    if (i < NB) {
        const int o = offsets[i] + blockSums[blockIdx.x];
        offsets[i] = o;
        cursor[i]  = o;
    }
    if (blockIdx.x == 0 && threadIdx.x == 0) offsets[NB] = NE;
}

__global__ __launch_bounds__(256) void scatter_kernel(
    const int* __restrict__ src, const int* __restrict__ dst,
    const int* __restrict__ rel, int* __restrict__ cursor,
    unsigned* __restrict__ packed)
{
    int e = blockIdx.x * 256 + threadIdx.x;
    if (e < NE) {
        const int key = dst[e] * NR + rel[e];
        const int pos = atomicAdd(&cursor[key], 1);
        packed[pos] = (unsigned)src[e];
    }
}

// ---------------------------------------------------------------------------
// Phase B v3 [proven r10]: one wave per NODE (8 segments). Quarter q owns
// relations q and q+4: 2 chains x unroll-2 = 16 loads in flight per wave.
// ---------------------------------------------------------------------------
__device__ __forceinline__ void accum8(float* acc, const uint4 u)
{
    const unsigned w[4] = {u.x, u.y, u.z, u.w};
    #pragma unroll
    for (int j = 0; j < 4; ++j) {
        acc[2 * j]     += __uint_as_float(w[j] << 16);
        acc[2 * j + 1] += __uint_as_float(w[j] & 0xFFFF0000u);
    }
}

__global__ __launch_bounds__(256) void agg_bf16_kernel(
    const __hip_bfloat16* __restrict__ Xb, const float* __restrict__ inv_norm,
    const int* __restrict__ offsets, const unsigned* __restrict__ packed,
    __hip_bfloat16* __restrict__ A)
{
    const int tid  = threadIdx.x;
    const int q    = (tid >> 4) & 3;                 // quarter 0..3
    const int l    = tid & 15;                       // lane in quarter
    const int node = blockIdx.x * 4 + (tid >> 6);    // wave -> node
    if (node >= NN) return;

    const int sA = node * NR + q;                    // relation q
    const int sB = sA + 4;                           // relation q+4

    int eA = offsets[sA];
    const int endA = offsets[sA + 1];
    int eB = offsets[sB];
    const int endB = offsets[sB + 1];

    float aA[8] = {0.f,0.f,0.f,0.f,0.f,0.f,0.f,0.f};
    float aB[8] = {0.f,0.f,0.f,0.f,0.f,0.f,0.f,0.f};

    while (__any((eA + 2 <= endA) || (eB + 2 <= endB))) {
        const bool dA = (eA + 2 <= endA);
        const bool dB = (eB + 2 <= endB);
        uint4 u0, u1, v0, v1;
        if (dA) {
            u0 = *(const uint4*)(Xb + (size_t)packed[eA] * DD + l * 8);
            u1 = *(const uint4*)(Xb + (size_t)packed[eA + 1] * DD + l * 8);
        }
        if (dB) {
            v0 = *(const uint4*)(Xb + (size_t)packed[eB] * DD + l * 8);
            v1 = *(const uint4*)(Xb + (size_t)packed[eB + 1] * DD + l * 8);
        }
        if (dA) { accum8(aA, u0); accum8(aA, u1); eA += 2; }
        if (dB) { accum8(aB, v0); accum8(aB, v1); eB += 2; }
    }
    if (eA < endA) {
        const uint4 u0 = *(const uint4*)(Xb + (size_t)packed[eA] * DD + l * 8);
        accum8(aA, u0);
    }
    if (eB < endB) {
        const uint4 v0 = *(const uint4*)(Xb + (size_t)packed[eB] * DD + l * 8);
        accum8(aB, v0);
    }

    const float invA = inv_norm[sA];
    const float invB = inv_norm[sB];
    __bf16 hA[8], hB[8];
    #pragma unroll
    for (int j = 0; j < 8; ++j) {
        hA[j] = (__bf16)(aA[j] * invA);
        hB[j] = (__bf16)(aB[j] * invB);
    }
    *(uint4*)(A + (size_t)node * KTOT + q * DD + l * 8)       = *(uint4*)hA;
    *(uint4*)(A + (size_t)node * KTOT + (q + 4) * DD + l * 8) = *(uint4*)hB;
}

// ---------------------------------------------------------------------------
// Phase C v4 [r10 structure + global_load_lds staging]:
// out = [A | Xb] @ [Wt stack]  (K = 1152, 9 chunks of 128)
// 128x128 tile, 4 waves (2x2), mfma_f32_16x16x32_bf16, 4x4 frags/wave.
// Staging via global_load_lds width=16: LDS dest linear (lane l -> base+l*16,
// i.e. [4 rows][16 slots]); swizzle achieved by PRE-SWIZZLING the global
// source column j_src = j ^ (row&7) (rule #21/m173). LDS contents bit-
// identical to r10's ds_write path; MFMA read loop unchanged.
// Tail block (n0+128 > NN) uses r10's bounds-checked reg staging.
// ---------------------------------------------------------------------------
__global__ __launch_bounds__(256) void mfma_gemm_kernel(
    const __hip_bfloat16* __restrict__ A, const __hip_bfloat16* __restrict__ Xb,
    const __hip_bfloat16* __restrict__ Wt, float* __restrict__ out)
{
    __shared__ __align__(16) char As[128 * 256];
    __shared__ __align__(16) char Bs[128 * 256];

    const int tid  = threadIdx.x;
    const int n0   = blockIdx.x * 128;
    const int lane = tid & 63;
    const int wid  = tid >> 6;
    const int wr   = wid >> 1, wc = wid & 1;
    const int l15  = lane & 15, kg = lane >> 4;
    const bool full = (n0 + 128 <= NN);

    f32x4 acc[4][4];
    #pragma unroll
    for (int mf = 0; mf < 4; ++mf)
        #pragma unroll
        for (int nf = 0; nf < 4; ++nf)
            acc[mf][nf] = (f32x4){0.f, 0.f, 0.f, 0.f};

    for (int c = 0; c < NR + 1; ++c) {
        const __hip_bfloat16* __restrict__ Ab =
            (c < NR) ? (A + (size_t)c * DD) : Xb;
        const size_t astr = (c < NR) ? (size_t)KTOT : (size_t)DD;
        const __hip_bfloat16* __restrict__ Wc = Wt + (size_t)c * DD * DD;

        if (full) {
            // wave wid stages A rows [wid*32, wid*32+32) and same B rows.
            // lane l -> row_local = l>>4 (0..3), slot j = l&15; LDS linear.
            const int rowl = lane >> 4;
            const int j    = lane & 15;
            #pragma unroll
            for (int it = 0; it < 8; ++it) {
                const int row  = wid * 32 + it * 4 + rowl;
                const int jSrc = j ^ (row & 7);
                gload_lds16(Ab + (size_t)(n0 + row) * astr + jSrc * 8,
                            As + (wid * 32 + it * 4) * 256);
                gload_lds16(Wc + (size_t)row * DD + jSrc * 8,
                            Bs + (wid * 32 + it * 4) * 256);
            }
        } else {
            // tail: r10 bounds-checked reg staging (bit-identical layout)
            #pragma unroll
            for (int it = 0; it < 8; ++it) {
                const int idx = tid + it * 256;
                const int row = idx >> 4, b = idx & 15;
                const int n = n0 + row;
                uint4 v = make_uint4(0u, 0u, 0u, 0u);
                if (n < NN)
                    v = *(const uint4*)(Ab + (size_t)n * astr + b * 8);
                *(uint4*)(As + row * 256 + ((b ^ (row & 7)) << 4)) = v;
                const uint4 w = *(const uint4*)(Wc + (size_t)row * DD + b * 8);
                *(uint4*)(Bs + row * 256 + ((b ^ (row & 7)) << 4)) = w;
            }
        }
        __syncthreads();

        #pragma unroll
        for (int ks = 0; ks < 4; ++ks) {
            const int b = ks * 4 + kg;
            bf16x8 af[4], bfr[4];
            #pragma unroll
            for (int mf = 0; mf < 4; ++mf) {
                const int row = wr * 64 + mf * 16 + l15;
                af[mf] = *(const bf16x8*)(As + row * 256 + ((b ^ (row & 7)) << 4));
            }
            #pragma unroll
            for (int nf = 0; nf < 4; ++nf) {
                const int row = wc * 64 + nf * 16 + l15;
                bfr[nf] = *(const bf16x8*)(Bs + row * 256 + ((b ^ (row & 7)) << 4));
            }
            #pragma unroll
            for (int mf = 0; mf < 4; ++mf)
                #pragma unroll
                for (int nf = 0; nf < 4; ++nf)
                    acc[mf][nf] = __builtin_amdgcn_mfma_f32_16x16x32_bf16(
                        af[mf], bfr[nf], acc[mf][nf], 0, 0, 0);
        }
        __syncthreads();
    }

    // epilogue: C/D layout col=lane&15, row=(lane>>4)*4+reg  [m89/m91]
    #pragma unroll
    for (int mf = 0; mf < 4; ++mf) {
        #pragma unroll
        for (int reg = 0; reg < 4; ++reg) {
            const int n = n0 + wr * 64 + mf * 16 + kg * 4 + reg;
            if (n < NN) {
                #pragma unroll
                for (int nf = 0; nf < 4; ++nf)
                    out[(size_t)n * DD + wc * 64 + nf * 16 + l15] = acc[mf][nf][reg];
            }
        }
    }
}

// ---------------------------------------------------------------------------
// Fallback (ws too small)
// ---------------------------------------------------------------------------
__global__ __launch_bounds__(256) void xform0_kernel(
    const float* __restrict__ X, const float* __restrict__ W0, float* __restrict__ out)
{
    __shared__ __align__(16) float Xs[64][XPAD];
    const int n0 = blockIdx.x * 64;
    const int tid = threadIdx.x;
    for (int t = tid; t < 64 * 32; t += 256) {
        const int row = t >> 5, g = t & 31;
        const int n = n0 + row;
        float4 v = make_float4(0.f, 0.f, 0.f, 0.f);
        if (n < NN) v = ((const float4*)(X + (size_t)n * DD))[g];
        *(float4*)&Xs[row][g * 4] = v;
    }
    __syncthreads();
    const int to = tid & 31, tn = tid >> 5;
    float acc[8][4];
    #pragma unroll
    for (int k = 0; k < 8; ++k)
        #pragma unroll
        for (int j = 0; j < 4; ++j) acc[k][j] = 0.f;
    for (int i = 0; i < DD; ++i) {
        const float4 w = ((const float4*)(W0 + (size_t)i * DD))[to];
        #pragma unroll
        for (int k = 0; k < 8; ++k) {
            const float xs = Xs[tn * 8 + k][i];
            acc[k][0] += xs * w.x; acc[k][1] += xs * w.y;
            acc[k][2] += xs * w.z; acc[k][3] += xs * w.w;
        }
    }
    #pragma unroll
    for (int k = 0; k < 8; ++k) {
        const int n = n0 + tn * 8 + k;
        if (n < NN)
            ((float4*)(out + (size_t)n * DD))[to] =
                make_float4(acc[k][0], acc[k][1], acc[k][2], acc[k][3]);
    }
}

__global__ __launch_bounds__(128) void edge_fallback_kernel(
    const float* __restrict__ X, const float* __restrict__ W,
    const float* __restrict__ inv_norm,
    const int* __restrict__ src, const int* __restrict__ dst,
    const int* __restrict__ rel, float* __restrict__ out)
{
    const int o = threadIdx.x;
    for (int e = blockIdx.x; e < NE; e += gridDim.x) {
        const int s = src[e], d = dst[e], r = rel[e];
        const float inv = inv_norm[(size_t)d * NR + r];
        const float* Xr = X + (size_t)s * DD;
        const float* Wr = W + (size_t)r * DD * DD;
        float a = 0.f;
        for (int i = 0; i < DD; ++i) a += Xr[i] * Wr[i * DD + o];
        unsafeAtomicAdd(out + (size_t)d * DD + o, a * inv);
    }
}

// ---------------------------------------------------------------------------
extern "C" void kernel_launch(void* const* d_in, const int* in_sizes, int n_in,
                              void* d_out, int out_size, void* d_ws, size_t ws_size,
                              hipStream_t stream)
{
    const float* X        = (const float*)d_in[0];
    const float* W        = (const float*)d_in[1];
    const float* W0       = (const float*)d_in[2];
    const float* inv_norm = (const float*)d_in[3];
    const int*   src      = (const int*)d_in[4];
    const int*   dst      = (const int*)d_in[5];
    const int*   rel      = (const int*)d_in[6];
    float* out = (float*)d_out;

    char* ws = (char*)d_ws;
    size_t off = 0;
    auto alloc = [&](size_t bytes) {
        void* p = ws + off;
        off += (bytes + 255) & ~(size_t)255;
        return p;
    };
    __hip_bfloat16* A  = (__hip_bfloat16*)alloc((size_t)NN * KTOT * sizeof(__hip_bfloat16));
    int*      offsets  = (int*)alloc((size_t)(NB + 1) * sizeof(int));
    int*      cursor   = (int*)alloc((size_t)NB * sizeof(int));
    int*      cnt      = (int*)alloc((size_t)NB * sizeof(int));
    unsigned* packed   = (unsigned*)alloc((size_t)NE * sizeof(unsigned));
    __hip_bfloat16* Wt = (__hip_bfloat16*)alloc((size_t)9 * DD * DD * sizeof(__hip_bfloat16));
    int*    blockSums  = (int*)alloc((size_t)NSCAN * sizeof(int));
    __hip_bfloat16* Xb = (__hip_bfloat16*)alloc((size_t)NN * DD * sizeof(__hip_bfloat16));

    if (ws_size >= off) {
        hipMemsetAsync(cnt, 0, (size_t)NB * sizeof(int), stream);
        histcvt_kernel<<<HIST_BLOCKS + CVT_BLOCKS, 256, 0, stream>>>(
            dst, rel, cnt, X, Xb, W, W0, Wt);
        scan1_kernel<<<NSCAN, 1024, 0, stream>>>(cnt, offsets, blockSums);
        scan2_kernel<<<1, 512, 0, stream>>>(blockSums);
        scan3_kernel<<<NSCAN, 1024, 0, stream>>>(offsets, cursor, blockSums);
        scatter_kernel<<<(NE + 255) / 256, 256, 0, stream>>>(src, dst, rel, cursor, packed);
        agg_bf16_kernel<<<(NN + 3) / 4, 256, 0, stream>>>(
            Xb, inv_norm, offsets, packed, A);
        mfma_gemm_kernel<<<(NN + 127) / 128, 256, 0, stream>>>(A, Xb, Wt, out);
    } else {
        xform0_kernel<<<(NN + 63) / 64, 256, 0, stream>>>(X, W0, out);
        edge_fallback_kernel<<<8192, 128, 0, stream>>>(X, W, inv_norm, src, dst, rel, out);
    }
}

// Round 15
// 182.341 us; speedup vs baseline: 1.2252x; 1.0352x over previous
//
#include <hip/hip_runtime.h>
#include <hip/hip_bf16.h>
#include <cstddef>

#define NN 50000
#define NR 8
#define NE 800000
#define DD 128
#define KTOT 1024                    // NR * DD
#define NB (NN * NR)                 // sort bins: key = dst*8 + rel
#define NSCAN ((NB + 1023) / 1024)   // 391
#define XPAD 136

#define HIST_BLOCKS ((NE + 255) / 256)       // 3125
#define NXCVT (NN * DD / 8)                  // 800000
#define NWCVT (9 * DD * DD)                  // 147456
#define CVT_BLOCKS ((NXCVT + NWCVT + 255) / 256)

#define NPASS 8                              // scatter range-partition passes
#define NODES_PER_PASS (NN / NPASS)          // 6250
#define SC_BLOCKS ((NE + 255) / 256)         // 3125 blocks per pass

typedef __bf16 bf16x8 __attribute__((ext_vector_type(8)));
typedef float  f32x4  __attribute__((ext_vector_type(4)));

// direct global->LDS DMA, 16 B per lane; LDS dest = wave-uniform base + lane*16
__device__ __forceinline__ void gload_lds16(const void* g, void* lds)
{
    __builtin_amdgcn_global_load_lds(
        (const __attribute__((address_space(1))) unsigned*)g,
        (__attribute__((address_space(3))) unsigned*)lds, 16, 0, 0);
}

// ---------------------------------------------------------------------------
// hist (counting sort pass 1) fused with X/W -> bf16 conversion  [proven r7-r14]
// ---------------------------------------------------------------------------
__global__ __launch_bounds__(256) void histcvt_kernel(
    const int* __restrict__ dst, const int* __restrict__ rel, int* __restrict__ cnt,
    const float* __restrict__ X, __hip_bfloat16* __restrict__ Xb,
    const float* __restrict__ W, const float* __restrict__ W0,
    __hip_bfloat16* __restrict__ Wt)
{
    const int bid = blockIdx.x;
    if (bid < HIST_BLOCKS) {
        const int e = bid * 256 + threadIdx.x;
        if (e < NE) atomicAdd(&cnt[dst[e] * NR + rel[e]], 1);
    } else {
        const int i = (bid - HIST_BLOCKS) * 256 + threadIdx.x;
        if (i < NXCVT) {
            const float4* xp = (const float4*)(X + (size_t)i * 8);
            const float4 a = xp[0], b = xp[1];
            __bf16 h[8] = {(__bf16)a.x, (__bf16)a.y, (__bf16)a.z, (__bf16)a.w,
                           (__bf16)b.x, (__bf16)b.y, (__bf16)b.z, (__bf16)b.w};
            *(uint4*)(Xb + (size_t)i * 8) = *(uint4*)h;
        } else {
            const int idx = i - NXCVT;
            if (idx < NWCVT) {
                const int c = idx >> 14;
                const int r = idx & 16383;
                const int n = r >> 7, k = r & 127;
                const float v = (c < NR) ? W[(size_t)c * DD * DD + k * DD + n]
                                         : W0[k * DD + n];
                Wt[idx] = __float2bfloat16(v);
            }
        }
    }
}

// 3-pass parallel exclusive scan over NB bins  [proven r4-r14]
__global__ __launch_bounds__(1024) void scan1_kernel(
    const int* __restrict__ cnt, int* __restrict__ offsets, int* __restrict__ blockSums)
{
    __shared__ int sm[1024];
    const int t = threadIdx.x;
    const int i = blockIdx.x * 1024 + t;
    const int v = (i < NB) ? cnt[i] : 0;
    sm[t] = v;
    __syncthreads();
    #pragma unroll
    for (int off = 1; off < 1024; off <<= 1) {
        int u = (t >= off) ? sm[t - off] : 0;
        __syncthreads();
        sm[t] += u;
        __syncthreads();
    }
    if (i < NB) offsets[i] = sm[t] - v;
    if (t == 1023) blockSums[blockIdx.x] = sm[1023];
}

__global__ __launch_bounds__(512) void scan2_kernel(int* __restrict__ blockSums)
{
    __shared__ int sm[512];
    const int t = threadIdx.x;
    const int v = (t < NSCAN) ? blockSums[t] : 0;
    sm[t] = v;
    __syncthreads();
    #pragma unroll
    for (int off = 1; off < 512; off <<= 1) {
        int u = (t >= off) ? sm[t - off] : 0;
        __syncthreads();
        sm[t] += u;
        __syncthreads();
    }
    if (t < NSCAN) blockSums[t] = sm[t] - v;
}

__global__ __launch_bounds__(1024) void scan3_kernel(
    int* __restrict__ offsets, int* __restrict__ cursor, const int* __restrict__ blockSums)
{
    const int i = blockIdx.x * 1024 + threadIdx.x;
    if (i < NB) {
        const int o = offsets[i] + blockSums[blockIdx.x];
        offsets[i] = o;
        cursor[i]  = o;
    }
    if (blockIdx.x == 0 && threadIdx.x == 0) offsets[NB] = NE;
}

// ---------------------------------------------------------------------------
// Range-partitioned scatter [r15]: pass p keeps dst in [p*6250,(p+1)*6250).
// Active cursor slice (200 KB) + packed slice (~200 KB ushort) stay
// L2-resident -> random stores coalesce in-cache; write amplification gone.
// dst/rel re-reads are coalesced streams (L3-resident after pass 0).
// ---------------------------------------------------------------------------
__global__ __launch_bounds__(256) void scatter_kernel(
    const int* __restrict__ src, const int* __restrict__ dst,
    const int* __restrict__ rel, int* __restrict__ cursor,
    unsigned short* __restrict__ packed)
{
    const int pass = blockIdx.x / SC_BLOCKS;
    const int e    = (blockIdx.x % SC_BLOCKS) * 256 + threadIdx.x;
    if (e >= NE) return;
    const int d = dst[e];
    const int lo = pass * NODES_PER_PASS;
    if (d < lo || d >= lo + NODES_PER_PASS) return;
    const int key = d * NR + rel[e];
    const int pos = atomicAdd(&cursor[key], 1);
    packed[pos] = (unsigned short)src[e];
}

// ---------------------------------------------------------------------------
// Phase B v3 [proven r10/r14]: one wave per NODE (8 segments). Quarter q owns
// relations q and q+4: 2 chains x unroll-2 = 16 loads in flight per wave.
// ---------------------------------------------------------------------------
__device__ __forceinline__ void accum8(float* acc, const uint4 u)
{
    const unsigned w[4] = {u.x, u.y, u.z, u.w};
    #pragma unroll
    for (int j = 0; j < 4; ++j) {
        acc[2 * j]     += __uint_as_float(w[j] << 16);
        acc[2 * j + 1] += __uint_as_float(w[j] & 0xFFFF0000u);
    }
}

__global__ __launch_bounds__(256) void agg_bf16_kernel(
    const __hip_bfloat16* __restrict__ Xb, const float* __restrict__ inv_norm,
    const int* __restrict__ offsets, const unsigned short* __restrict__ packed,
    __hip_bfloat16* __restrict__ A)
{
    const int tid  = threadIdx.x;
    const int q    = (tid >> 4) & 3;                 // quarter 0..3
    const int l    = tid & 15;                       // lane in quarter
    const int node = blockIdx.x * 4 + (tid >> 6);    // wave -> node
    if (node >= NN) return;

    const int sA = node * NR + q;                    // relation q
    const int sB = sA + 4;                           // relation q+4

    int eA = offsets[sA];
    const int endA = offsets[sA + 1];
    int eB = offsets[sB];
    const int endB = offsets[sB + 1];

    float aA[8] = {0.f,0.f,0.f,0.f,0.f,0.f,0.f,0.f};
    float aB[8] = {0.f,0.f,0.f,0.f,0.f,0.f,0.f,0.f};

    while (__any((eA + 2 <= endA) || (eB + 2 <= endB))) {
        const bool dA = (eA + 2 <= endA);
        const bool dB = (eB + 2 <= endB);
        uint4 u0, u1, v0, v1;
        if (dA) {
            u0 = *(const uint4*)(Xb + (size_t)packed[eA] * DD + l * 8);
            u1 = *(const uint4*)(Xb + (size_t)packed[eA + 1] * DD + l * 8);
        }
        if (dB) {
            v0 = *(const uint4*)(Xb + (size_t)packed[eB] * DD + l * 8);
            v1 = *(const uint4*)(Xb + (size_t)packed[eB + 1] * DD + l * 8);
        }
        if (dA) { accum8(aA, u0); accum8(aA, u1); eA += 2; }
        if (dB) { accum8(aB, v0); accum8(aB, v1); eB += 2; }
    }
    if (eA < endA) {
        const uint4 u0 = *(const uint4*)(Xb + (size_t)packed[eA] * DD + l * 8);
        accum8(aA, u0);
    }
    if (eB < endB) {
        const uint4 v0 = *(const uint4*)(Xb + (size_t)packed[eB] * DD + l * 8);
        accum8(aB, v0);
    }

    const float invA = inv_norm[sA];
    const float invB = inv_norm[sB];
    __bf16 hA[8], hB[8];
    #pragma unroll
    for (int j = 0; j < 8; ++j) {
        hA[j] = (__bf16)(aA[j] * invA);
        hB[j] = (__bf16)(aB[j] * invB);
    }
    *(uint4*)(A + (size_t)node * KTOT + q * DD + l * 8)       = *(uint4*)hA;
    *(uint4*)(A + (size_t)node * KTOT + (q + 4) * DD + l * 8) = *(uint4*)hB;
}

// ---------------------------------------------------------------------------
// Phase C v4 [proven r14]: r10 structure + global_load_lds width-16 staging.
// Swizzle via pre-swizzled global source column (rule #21/m173); LDS linear.
// Tail block keeps bounds-checked reg staging.
// ---------------------------------------------------------------------------
__global__ __launch_bounds__(256) void mfma_gemm_kernel(
    const __hip_bfloat16* __restrict__ A, const __hip_bfloat16* __restrict__ Xb,
    const __hip_bfloat16* __restrict__ Wt, float* __restrict__ out)
{
    __shared__ __align__(16) char As[128 * 256];
    __shared__ __align__(16) char Bs[128 * 256];

    const int tid  = threadIdx.x;
    const int n0   = blockIdx.x * 128;
    const int lane = tid & 63;
    const int wid  = tid >> 6;
    const int wr   = wid >> 1, wc = wid & 1;
    const int l15  = lane & 15, kg = lane >> 4;
    const bool full = (n0 + 128 <= NN);

    f32x4 acc[4][4];
    #pragma unroll
    for (int mf = 0; mf < 4; ++mf)
        #pragma unroll
        for (int nf = 0; nf < 4; ++nf)
            acc[mf][nf] = (f32x4){0.f, 0.f, 0.f, 0.f};

    for (int c = 0; c < NR + 1; ++c) {
        const __hip_bfloat16* __restrict__ Ab =
            (c < NR) ? (A + (size_t)c * DD) : Xb;
        const size_t astr = (c < NR) ? (size_t)KTOT : (size_t)DD;
        const __hip_bfloat16* __restrict__ Wc = Wt + (size_t)c * DD * DD;

        if (full) {
            const int rowl = lane >> 4;
            const int j    = lane & 15;
            #pragma unroll
            for (int it = 0; it < 8; ++it) {
                const int row  = wid * 32 + it * 4 + rowl;
                const int jSrc = j ^ (row & 7);
                gload_lds16(Ab + (size_t)(n0 + row) * astr + jSrc * 8,
                            As + (wid * 32 + it * 4) * 256);
                gload_lds16(Wc + (size_t)row * DD + jSrc * 8,
                            Bs + (wid * 32 + it * 4) * 256);
            }
        } else {
            #pragma unroll
            for (int it = 0; it < 8; ++it) {
                const int idx = tid + it * 256;
                const int row = idx >> 4, b = idx & 15;
                const int n = n0 + row;
                uint4 v = make_uint4(0u, 0u, 0u, 0u);
                if (n < NN)
                    v = *(const uint4*)(Ab + (size_t)n * astr + b * 8);
                *(uint4*)(As + row * 256 + ((b ^ (row & 7)) << 4)) = v;
                const uint4 w = *(const uint4*)(Wc + (size_t)row * DD + b * 8);
                *(uint4*)(Bs + row * 256 + ((b ^ (row & 7)) << 4)) = w;
            }
        }
        __syncthreads();

        #pragma unroll
        for (int ks = 0; ks < 4; ++ks) {
            const int b = ks * 4 + kg;
            bf16x8 af[4], bfr[4];
            #pragma unroll
            for (int mf = 0; mf < 4; ++mf) {
                const int row = wr * 64 + mf * 16 + l15;
                af[mf] = *(const bf16x8*)(As + row * 256 + ((b ^ (row & 7)) << 4));
            }
            #pragma unroll
            for (int nf = 0; nf < 4; ++nf) {
                const int row = wc * 64 + nf * 16 + l15;
                bfr[nf] = *(const bf16x8*)(Bs + row * 256 + ((b ^ (row & 7)) << 4));
            }
            #pragma unroll
            for (int mf = 0; mf < 4; ++mf)
                #pragma unroll
                for (int nf = 0; nf < 4; ++nf)
                    acc[mf][nf] = __builtin_amdgcn_mfma_f32_16x16x32_bf16(
                        af[mf], bfr[nf], acc[mf][nf], 0, 0, 0);
        }
        __syncthreads();
    }

    // epilogue: C/D layout col=lane&15, row=(lane>>4)*4+reg  [m89/m91]
    #pragma unroll
    for (int mf = 0; mf < 4; ++mf) {
        #pragma unroll
        for (int reg = 0; reg < 4; ++reg) {
            const int n = n0 + wr * 64 + mf * 16 + kg * 4 + reg;
            if (n < NN) {
                #pragma unroll
                for (int nf = 0; nf < 4; ++nf)
                    out[(size_t)n * DD + wc * 64 + nf * 16 + l15] = acc[mf][nf][reg];
            }
        }
    }
}

// ---------------------------------------------------------------------------
// Fallback (ws too small)
// ---------------------------------------------------------------------------
__global__ __launch_bounds__(256) void xform0_kernel(
    const float* __restrict__ X, const float* __restrict__ W0, float* __restrict__ out)
{
    __shared__ __align__(16) float Xs[64][XPAD];
    const int n0 = blockIdx.x * 64;
    const int tid = threadIdx.x;
    for (int t = tid; t < 64 * 32; t += 256) {
        const int row = t >> 5, g = t & 31;
        const int n = n0 + row;
        float4 v = make_float4(0.f, 0.f, 0.f, 0.f);
        if (n < NN) v = ((const float4*)(X + (size_t)n * DD))[g];
        *(float4*)&Xs[row][g * 4] = v;
    }
    __syncthreads();
    const int to = tid & 31, tn = tid >> 5;
    float acc[8][4];
    #pragma unroll
    for (int k = 0; k < 8; ++k)
        #pragma unroll
        for (int j = 0; j < 4; ++j) acc[k][j] = 0.f;
    for (int i = 0; i < DD; ++i) {
        const float4 w = ((const float4*)(W0 + (size_t)i * DD))[to];
        #pragma unroll
        for (int k = 0; k < 8; ++k) {
            const float xs = Xs[tn * 8 + k][i];
            acc[k][0] += xs * w.x; acc[k][1] += xs * w.y;
            acc[k][2] += xs * w.z; acc[k][3] += xs * w.w;
        }
    }
    #pragma unroll
    for (int k = 0; k < 8; ++k) {
        const int n = n0 + tn * 8 + k;
        if (n < NN)
            ((float4*)(out + (size_t)n * DD))[to] =
                make_float4(acc[k][0], acc[k][1], acc[k][2], acc[k][3]);
    }
}

__global__ __launch_bounds__(128) void edge_fallback_kernel(
    const float* __restrict__ X, const float* __restrict__ W,
    const float* __restrict__ inv_norm,
    const int* __restrict__ src, const int* __restrict__ dst,
    const int* __restrict__ rel, float* __restrict__ out)
{
    const int o = threadIdx.x;
    for (int e = blockIdx.x; e < NE; e += gridDim.x) {
        const int s = src[e], d = dst[e], r = rel[e];
        const float inv = inv_norm[(size_t)d * NR + r];
        const float* Xr = X + (size_t)s * DD;
        const float* Wr = W + (size_t)r * DD * DD;
        float a = 0.f;
        for (int i = 0; i < DD; ++i) a += Xr[i] * Wr[i * DD + o];
        unsafeAtomicAdd(out + (size_t)d * DD + o, a * inv);
    }
}

// ---------------------------------------------------------------------------
extern "C" void kernel_launch(void* const* d_in, const int* in_sizes, int n_in,
                              void* d_out, int out_size, void* d_ws, size_t ws_size,
                              hipStream_t stream)
{
    const float* X        = (const float*)d_in[0];
    const float* W        = (const float*)d_in[1];
    const float* W0       = (const float*)d_in[2];
    const float* inv_norm = (const float*)d_in[3];
    const int*   src      = (const int*)d_in[4];
    const int*   dst      = (const int*)d_in[5];
    const int*   rel      = (const int*)d_in[6];
    float* out = (float*)d_out;

    char* ws = (char*)d_ws;
    size_t off = 0;
    auto alloc = [&](size_t bytes) {
        void* p = ws + off;
        off += (bytes + 255) & ~(size_t)255;
        return p;
    };
    __hip_bfloat16* A     = (__hip_bfloat16*)alloc((size_t)NN * KTOT * sizeof(__hip_bfloat16));
    int*      offsets     = (int*)alloc((size_t)(NB + 1) * sizeof(int));
    int*      cursor      = (int*)alloc((size_t)NB * sizeof(int));
    int*      cnt         = (int*)alloc((size_t)NB * sizeof(int));
    unsigned short* packed = (unsigned short*)alloc((size_t)NE * sizeof(unsigned short));
    __hip_bfloat16* Wt    = (__hip_bfloat16*)alloc((size_t)9 * DD * DD * sizeof(__hip_bfloat16));
    int*    blockSums     = (int*)alloc((size_t)NSCAN * sizeof(int));
    __hip_bfloat16* Xb    = (__hip_bfloat16*)alloc((size_t)NN * DD * sizeof(__hip_bfloat16));

    if (ws_size >= off) {
        hipMemsetAsync(cnt, 0, (size_t)NB * sizeof(int), stream);
        histcvt_kernel<<<HIST_BLOCKS + CVT_BLOCKS, 256, 0, stream>>>(
            dst, rel, cnt, X, Xb, W, W0, Wt);
        scan1_kernel<<<NSCAN, 1024, 0, stream>>>(cnt, offsets, blockSums);
        scan2_kernel<<<1, 512, 0, stream>>>(blockSums);
        scan3_kernel<<<NSCAN, 1024, 0, stream>>>(offsets, cursor, blockSums);
        scatter_kernel<<<NPASS * SC_BLOCKS, 256, 0, stream>>>(
            src, dst, rel, cursor, packed);
        agg_bf16_kernel<<<(NN + 3) / 4, 256, 0, stream>>>(
            Xb, inv_norm, offsets, packed, A);
        mfma_gemm_kernel<<<(NN + 127) / 128, 256, 0, stream>>>(A, Xb, Wt, out);
    } else {
        xform0_kernel<<<(NN + 63) / 64, 256, 0, stream>>>(X, W0, out);
        edge_fallback_kernel<<<8192, 128, 0, stream>>>(X, W, inv_norm, src, dst, rel, out);
    }
}

// Round 16
// 171.382 us; speedup vs baseline: 1.3036x; 1.0639x over previous
//
#include <hip/hip_runtime.h>
#include <hip/hip_bf16.h>
#include <cstddef>

#define NN 50000
#define NR 8
#define NE 800000
#define DD 128
#define KTOT 1024                    // NR * DD
#define NB (NN * NR)                 // sort bins: key = dst*8 + rel
#define NSCAN ((NB + 1023) / 1024)   // 391
#define XPAD 136

#define HIST_BLOCKS ((NE + 255) / 256)       // 3125
#define NXCVT (NN * DD / 8)                  // 800000
#define NWCVT (9 * DD * DD)                  // 147456
#define CVT_BLOCKS ((NXCVT + NWCVT + 255) / 256)

#define NPASS 8                              // scatter range-partition passes
#define NODES_PER_PASS (NN / NPASS)          // 6250
#define SC_BLOCKS ((NE + 255) / 256)         // 3125 blocks per pass

typedef __bf16 bf16x8 __attribute__((ext_vector_type(8)));
typedef float  f32x4  __attribute__((ext_vector_type(4)));

// direct global->LDS DMA, 16 B per lane; LDS dest = wave-uniform base + lane*16
__device__ __forceinline__ void gload_lds16(const void* g, void* lds)
{
    __builtin_amdgcn_global_load_lds(
        (const __attribute__((address_space(1))) unsigned*)g,
        (__attribute__((address_space(3))) unsigned*)lds, 16, 0, 0);
}

// ---------------------------------------------------------------------------
// hist (counting sort pass 1) fused with X/W -> bf16 conversion  [proven r7-r15]
// ---------------------------------------------------------------------------
__global__ __launch_bounds__(256) void histcvt_kernel(
    const int* __restrict__ dst, const int* __restrict__ rel, int* __restrict__ cnt,
    const float* __restrict__ X, __hip_bfloat16* __restrict__ Xb,
    const float* __restrict__ W, const float* __restrict__ W0,
    __hip_bfloat16* __restrict__ Wt)
{
    const int bid = blockIdx.x;
    if (bid < HIST_BLOCKS) {
        const int e = bid * 256 + threadIdx.x;
        if (e < NE) atomicAdd(&cnt[dst[e] * NR + rel[e]], 1);
    } else {
        const int i = (bid - HIST_BLOCKS) * 256 + threadIdx.x;
        if (i < NXCVT) {
            const float4* xp = (const float4*)(X + (size_t)i * 8);
            const float4 a = xp[0], b = xp[1];
            __bf16 h[8] = {(__bf16)a.x, (__bf16)a.y, (__bf16)a.z, (__bf16)a.w,
                           (__bf16)b.x, (__bf16)b.y, (__bf16)b.z, (__bf16)b.w};
            *(uint4*)(Xb + (size_t)i * 8) = *(uint4*)h;
        } else {
            const int idx = i - NXCVT;
            if (idx < NWCVT) {
                const int c = idx >> 14;
                const int r = idx & 16383;
                const int n = r >> 7, k = r & 127;
                const float v = (c < NR) ? W[(size_t)c * DD * DD + k * DD + n]
                                         : W0[k * DD + n];
                Wt[idx] = __float2bfloat16(v);
            }
        }
    }
}

// 3-pass parallel exclusive scan over NB bins  [proven r4-r15]
__global__ __launch_bounds__(1024) void scan1_kernel(
    const int* __restrict__ cnt, int* __restrict__ offsets, int* __restrict__ blockSums)
{
    __shared__ int sm[1024];
    const int t = threadIdx.x;
    const int i = blockIdx.x * 1024 + t;
    const int v = (i < NB) ? cnt[i] : 0;
    sm[t] = v;
    __syncthreads();
    #pragma unroll
    for (int off = 1; off < 1024; off <<= 1) {
        int u = (t >= off) ? sm[t - off] : 0;
        __syncthreads();
        sm[t] += u;
        __syncthreads();
    }
    if (i < NB) offsets[i] = sm[t] - v;
    if (t == 1023) blockSums[blockIdx.x] = sm[1023];
}

__global__ __launch_bounds__(512) void scan2_kernel(int* __restrict__ blockSums)
{
    __shared__ int sm[512];
    const int t = threadIdx.x;
    const int v = (t < NSCAN) ? blockSums[t] : 0;
    sm[t] = v;
    __syncthreads();
    #pragma unroll
    for (int off = 1; off < 512; off <<= 1) {
        int u = (t >= off) ? sm[t - off] : 0;
        __syncthreads();
        sm[t] += u;
        __syncthreads();
    }
    if (t < NSCAN) blockSums[t] = sm[t] - v;
}

__global__ __launch_bounds__(1024) void scan3_kernel(
    int* __restrict__ offsets, int* __restrict__ cursor, const int* __restrict__ blockSums)
{
    const int i = blockIdx.x * 1024 + threadIdx.x;
    if (i < NB) {
        const int o = offsets[i] + blockSums[blockIdx.x];
        offsets[i] = o;
        cursor[i]  = o;
    }
    if (blockIdx.x == 0 && threadIdx.x == 0) offsets[NB] = NE;
}

// ---------------------------------------------------------------------------
// Range-partitioned scatter [proven r15]: pass p keeps dst in its 6250-node
// range; active cursor+packed slices stay L2-resident (no write amplification)
// ---------------------------------------------------------------------------
__global__ __launch_bounds__(256) void scatter_kernel(
    const int* __restrict__ src, const int* __restrict__ dst,
    const int* __restrict__ rel, int* __restrict__ cursor,
    unsigned short* __restrict__ packed)
{
    const int pass = blockIdx.x / SC_BLOCKS;
    const int e    = (blockIdx.x % SC_BLOCKS) * 256 + threadIdx.x;
    if (e >= NE) return;
    const int d = dst[e];
    const int lo = pass * NODES_PER_PASS;
    if (d < lo || d >= lo + NODES_PER_PASS) return;
    const int key = d * NR + rel[e];
    const int pos = atomicAdd(&cursor[key], 1);
    packed[pos] = (unsigned short)src[e];
}

// ---------------------------------------------------------------------------
// Phase B v3 [proven r10-r15]: one wave per NODE (8 segments). Quarter q owns
// relations q and q+4: 2 chains x unroll-2 = 16 loads in flight per wave.
// ---------------------------------------------------------------------------
__device__ __forceinline__ void accum8(float* acc, const uint4 u)
{
    const unsigned w[4] = {u.x, u.y, u.z, u.w};
    #pragma unroll
    for (int j = 0; j < 4; ++j) {
        acc[2 * j]     += __uint_as_float(w[j] << 16);
        acc[2 * j + 1] += __uint_as_float(w[j] & 0xFFFF0000u);
    }
}

__global__ __launch_bounds__(256) void agg_bf16_kernel(
    const __hip_bfloat16* __restrict__ Xb, const float* __restrict__ inv_norm,
    const int* __restrict__ offsets, const unsigned short* __restrict__ packed,
    __hip_bfloat16* __restrict__ A)
{
    const int tid  = threadIdx.x;
    const int q    = (tid >> 4) & 3;                 // quarter 0..3
    const int l    = tid & 15;                       // lane in quarter
    const int node = blockIdx.x * 4 + (tid >> 6);    // wave -> node
    if (node >= NN) return;

    const int sA = node * NR + q;                    // relation q
    const int sB = sA + 4;                           // relation q+4

    int eA = offsets[sA];
    const int endA = offsets[sA + 1];
    int eB = offsets[sB];
    const int endB = offsets[sB + 1];

    float aA[8] = {0.f,0.f,0.f,0.f,0.f,0.f,0.f,0.f};
    float aB[8] = {0.f,0.f,0.f,0.f,0.f,0.f,0.f,0.f};

    while (__any((eA + 2 <= endA) || (eB + 2 <= endB))) {
        const bool dA = (eA + 2 <= endA);
        const bool dB = (eB + 2 <= endB);
        uint4 u0, u1, v0, v1;
        if (dA) {
            u0 = *(const uint4*)(Xb + (size_t)packed[eA] * DD + l * 8);
            u1 = *(const uint4*)(Xb + (size_t)packed[eA + 1] * DD + l * 8);
        }
        if (dB) {
            v0 = *(const uint4*)(Xb + (size_t)packed[eB] * DD + l * 8);
            v1 = *(const uint4*)(Xb + (size_t)packed[eB + 1] * DD + l * 8);
        }
        if (dA) { accum8(aA, u0); accum8(aA, u1); eA += 2; }
        if (dB) { accum8(aB, v0); accum8(aB, v1); eB += 2; }
    }
    if (eA < endA) {
        const uint4 u0 = *(const uint4*)(Xb + (size_t)packed[eA] * DD + l * 8);
        accum8(aA, u0);
    }
    if (eB < endB) {
        const uint4 v0 = *(const uint4*)(Xb + (size_t)packed[eB] * DD + l * 8);
        accum8(aB, v0);
    }

    const float invA = inv_norm[sA];
    const float invB = inv_norm[sB];
    __bf16 hA[8], hB[8];
    #pragma unroll
    for (int j = 0; j < 8; ++j) {
        hA[j] = (__bf16)(aA[j] * invA);
        hB[j] = (__bf16)(aB[j] * invB);
    }
    *(uint4*)(A + (size_t)node * KTOT + q * DD + l * 8)       = *(uint4*)hA;
    *(uint4*)(A + (size_t)node * KTOT + (q + 4) * DD + l * 8) = *(uint4*)hB;
}

// ---------------------------------------------------------------------------
// Phase C v5 [r16]: 64-row tiles (782 blocks), both operands via gload_lds
// (r14-proven staging, swizzle by pre-swizzled global source column).
// LDS 48 KB (As 16K + Bs 32K) -> 3 blocks/CU = 12 waves/CU for a
// memory-bound skinny GEMM (TLP was the r14 limiter at 2 blocks/CU).
// Waves: wr = rows wr*32..+31 (mf 0..1), wc = cols wc*64..+63 (nf 0..3).
// ---------------------------------------------------------------------------
__global__ __launch_bounds__(256) void mfma_gemm_kernel(
    const __hip_bfloat16* __restrict__ A, const __hip_bfloat16* __restrict__ Xb,
    const __hip_bfloat16* __restrict__ Wt, float* __restrict__ out)
{
    __shared__ __align__(16) char As[64 * 256];    // 16 KB
    __shared__ __align__(16) char Bs[128 * 256];   // 32 KB

    const int tid  = threadIdx.x;
    const int n0   = blockIdx.x * 64;
    const int lane = tid & 63;
    const int wid  = tid >> 6;
    const int wr   = wid >> 1, wc = wid & 1;
    const int l15  = lane & 15, kg = lane >> 4;
    const bool full = (n0 + 64 <= NN);

    f32x4 acc[2][4];
    #pragma unroll
    for (int mf = 0; mf < 2; ++mf)
        #pragma unroll
        for (int nf = 0; nf < 4; ++nf)
            acc[mf][nf] = (f32x4){0.f, 0.f, 0.f, 0.f};

    for (int c = 0; c < NR + 1; ++c) {
        const __hip_bfloat16* __restrict__ Ab =
            (c < NR) ? (A + (size_t)c * DD) : Xb;
        const size_t astr = (c < NR) ? (size_t)KTOT : (size_t)DD;
        const __hip_bfloat16* __restrict__ Wc = Wt + (size_t)c * DD * DD;

        if (full) {
            const int rowl = lane >> 4;
            const int j    = lane & 15;
            // As: wave wid stages rows [wid*16, wid*16+16)  (4 rows/instr)
            #pragma unroll
            for (int it = 0; it < 4; ++it) {
                const int row  = wid * 16 + it * 4 + rowl;
                const int jSrc = j ^ (row & 7);
                gload_lds16(Ab + (size_t)(n0 + row) * astr + jSrc * 8,
                            As + (wid * 16 + it * 4) * 256);
            }
            // Bs: wave wid stages rows [wid*32, wid*32+32)
            #pragma unroll
            for (int it = 0; it < 8; ++it) {
                const int row  = wid * 32 + it * 4 + rowl;
                const int jSrc = j ^ (row & 7);
                gload_lds16(Wc + (size_t)row * DD + jSrc * 8,
                            Bs + (wid * 32 + it * 4) * 256);
            }
        } else {
            // tail: bounds-checked reg staging (bit-identical layout)
            #pragma unroll
            for (int it = 0; it < 4; ++it) {
                const int idx = tid + it * 256;
                const int row = idx >> 4, b = idx & 15;
                const int n = n0 + row;
                uint4 v = make_uint4(0u, 0u, 0u, 0u);
                if (n < NN)
                    v = *(const uint4*)(Ab + (size_t)n * astr + b * 8);
                *(uint4*)(As + row * 256 + ((b ^ (row & 7)) << 4)) = v;
            }
            #pragma unroll
            for (int it = 0; it < 8; ++it) {
                const int idx = tid + it * 256;
                const int row = idx >> 4, b = idx & 15;
                const uint4 w = *(const uint4*)(Wc + (size_t)row * DD + b * 8);
                *(uint4*)(Bs + row * 256 + ((b ^ (row & 7)) << 4)) = w;
            }
        }
        __syncthreads();

        #pragma unroll
        for (int ks = 0; ks < 4; ++ks) {
            const int b = ks * 4 + kg;
            bf16x8 af[2], bfr[4];
            #pragma unroll
            for (int mf = 0; mf < 2; ++mf) {
                const int row = wr * 32 + mf * 16 + l15;
                af[mf] = *(const bf16x8*)(As + row * 256 + ((b ^ (row & 7)) << 4));
            }
            #pragma unroll
            for (int nf = 0; nf < 4; ++nf) {
                const int brow = wc * 64 + nf * 16 + l15;
                bfr[nf] = *(const bf16x8*)(Bs + brow * 256 + ((b ^ (brow & 7)) << 4));
            }
            #pragma unroll
            for (int mf = 0; mf < 2; ++mf)
                #pragma unroll
                for (int nf = 0; nf < 4; ++nf)
                    acc[mf][nf] = __builtin_amdgcn_mfma_f32_16x16x32_bf16(
                        af[mf], bfr[nf], acc[mf][nf], 0, 0, 0);
        }
        __syncthreads();
    }

    // epilogue: C/D layout col=lane&15, row=(lane>>4)*4+reg  [m89/m91]
    #pragma unroll
    for (int mf = 0; mf < 2; ++mf) {
        #pragma unroll
        for (int reg = 0; reg < 4; ++reg) {
            const int n = n0 + wr * 32 + mf * 16 + kg * 4 + reg;
            if (n < NN) {
                #pragma unroll
                for (int nf = 0; nf < 4; ++nf)
                    out[(size_t)n * DD + wc * 64 + nf * 16 + l15] = acc[mf][nf][reg];
            }
        }
    }
}

// ---------------------------------------------------------------------------
// Fallback (ws too small)
// ---------------------------------------------------------------------------
__global__ __launch_bounds__(256) void xform0_kernel(
    const float* __restrict__ X, const float* __restrict__ W0, float* __restrict__ out)
{
    __shared__ __align__(16) float Xs[64][XPAD];
    const int n0 = blockIdx.x * 64;
    const int tid = threadIdx.x;
    for (int t = tid; t < 64 * 32; t += 256) {
        const int row = t >> 5, g = t & 31;
        const int n = n0 + row;
        float4 v = make_float4(0.f, 0.f, 0.f, 0.f);
        if (n < NN) v = ((const float4*)(X + (size_t)n * DD))[g];
        *(float4*)&Xs[row][g * 4] = v;
    }
    __syncthreads();
    const int to = tid & 31, tn = tid >> 5;
    float acc[8][4];
    #pragma unroll
    for (int k = 0; k < 8; ++k)
        #pragma unroll
        for (int j = 0; j < 4; ++j) acc[k][j] = 0.f;
    for (int i = 0; i < DD; ++i) {
        const float4 w = ((const float4*)(W0 + (size_t)i * DD))[to];
        #pragma unroll
        for (int k = 0; k < 8; ++k) {
            const float xs = Xs[tn * 8 + k][i];
            acc[k][0] += xs * w.x; acc[k][1] += xs * w.y;
            acc[k][2] += xs * w.z; acc[k][3] += xs * w.w;
        }
    }
    #pragma unroll
    for (int k = 0; k < 8; ++k) {
        const int n = n0 + tn * 8 + k;
        if (n < NN)
            ((float4*)(out + (size_t)n * DD))[to] =
                make_float4(acc[k][0], acc[k][1], acc[k][2], acc[k][3]);
    }
}

__global__ __launch_bounds__(128) void edge_fallback_kernel(
    const float* __restrict__ X, const float* __restrict__ W,
    const float* __restrict__ inv_norm,
    const int* __restrict__ src, const int* __restrict__ dst,
    const int* __restrict__ rel, float* __restrict__ out)
{
    const int o = threadIdx.x;
    for (int e = blockIdx.x; e < NE; e += gridDim.x) {
        const int s = src[e], d = dst[e], r = rel[e];
        const float inv = inv_norm[(size_t)d * NR + r];
        const float* Xr = X + (size_t)s * DD;
        const float* Wr = W + (size_t)r * DD * DD;
        float a = 0.f;
        for (int i = 0; i < DD; ++i) a += Xr[i] * Wr[i * DD + o];
        unsafeAtomicAdd(out + (size_t)d * DD + o, a * inv);
    }
}

// ---------------------------------------------------------------------------
extern "C" void kernel_launch(void* const* d_in, const int* in_sizes, int n_in,
                              void* d_out, int out_size, void* d_ws, size_t ws_size,
                              hipStream_t stream)
{
    const float* X        = (const float*)d_in[0];
    const float* W        = (const float*)d_in[1];
    const float* W0       = (const float*)d_in[2];
    const float* inv_norm = (const float*)d_in[3];
    const int*   src      = (const int*)d_in[4];
    const int*   dst      = (const int*)d_in[5];
    const int*   rel      = (const int*)d_in[6];
    float* out = (float*)d_out;

    char* ws = (char*)d_ws;
    size_t off = 0;
    auto alloc = [&](size_t bytes) {
        void* p = ws + off;
        off += (bytes + 255) & ~(size_t)255;
        return p;
    };
    __hip_bfloat16* A     = (__hip_bfloat16*)alloc((size_t)NN * KTOT * sizeof(__hip_bfloat16));
    int*      offsets     = (int*)alloc((size_t)(NB + 1) * sizeof(int));
    int*      cursor      = (int*)alloc((size_t)NB * sizeof(int));
    int*      cnt         = (int*)alloc((size_t)NB * sizeof(int));
    unsigned short* packed = (unsigned short*)alloc((size_t)NE * sizeof(unsigned short));
    __hip_bfloat16* Wt    = (__hip_bfloat16*)alloc((size_t)9 * DD * DD * sizeof(__hip_bfloat16));
    int*    blockSums     = (int*)alloc((size_t)NSCAN * sizeof(int));
    __hip_bfloat16* Xb    = (__hip_bfloat16*)alloc((size_t)NN * DD * sizeof(__hip_bfloat16));

    if (ws_size >= off) {
        hipMemsetAsync(cnt, 0, (size_t)NB * sizeof(int), stream);
        histcvt_kernel<<<HIST_BLOCKS + CVT_BLOCKS, 256, 0, stream>>>(
            dst, rel, cnt, X, Xb, W, W0, Wt);
        scan1_kernel<<<NSCAN, 1024, 0, stream>>>(cnt, offsets, blockSums);
        scan2_kernel<<<1, 512, 0, stream>>>(blockSums);
        scan3_kernel<<<NSCAN, 1024, 0, stream>>>(offsets, cursor, blockSums);
        scatter_kernel<<<NPASS * SC_BLOCKS, 256, 0, stream>>>(
            src, dst, rel, cursor, packed);
        agg_bf16_kernel<<<(NN + 3) / 4, 256, 0, stream>>>(
            Xb, inv_norm, offsets, packed, A);
        mfma_gemm_kernel<<<(NN + 63) / 64, 256, 0, stream>>>(A, Xb, Wt, out);
    } else {
        xform0_kernel<<<(NN + 63) / 64, 256, 0, stream>>>(X, W0, out);
        edge_fallback_kernel<<<8192, 128, 0, stream>>>(X, W, inv_norm, src, dst, rel, out);
    }
}